// Round 8
// baseline (1291.861 us; speedup 1.0000x reference)
//
#include <hip/hip_runtime.h>
#include <hip/hip_bf16.h>

// ---------------------------------------------------------------------------
// VQ-VAE forward. R18: deconv dedup retry at HALVED tile size.
// R17 analysis: t4 is LDS-read-bound (13 reads : 26 MFMA per tap-wave;
// ~368k LDS cyc/CU vs 79us MFMA floor). R15's dedup failed at TR=7 because
// acc[7][4]=112 VGPR + staging + A ~= 200+ hit the budget; at TR=4 the same
// structure needs ~130. Dedup: wave = (tile-half x co-half), 64 co/wave
// (4 A-frags), 4 MFMA per B ds_read_b128 -> B-reads halved, MFMA unchanged.
//  - t4: TR=4 (y=7, NT 4/3); t3: TR=4 (y=6, NT 3/3 balanced);
//    t1: TR=3 (y=3, NT 1/1 balanced, fixes 1-block/CU occupancy).
// KEPT: conv2/conv3 R13 template (conv2-dedup abandoned: compiler pins 128
// VGPR and serializes A-dbuf regardless of budget attrs); vq-fused dict/enc
// losses (+rec-only loss kernel); R13 linear LDS slot + PW padding.
// ---------------------------------------------------------------------------

#define B_ 256

typedef __attribute__((ext_vector_type(8))) short s16x8;
typedef __attribute__((ext_vector_type(4))) short s16x4;
typedef __attribute__((ext_vector_type(8))) _Float16 f16x8;
typedef __attribute__((ext_vector_type(4))) float f32x4;

__device__ inline ushort f2bf(float f) {
  union { __hip_bfloat16 h; ushort u; } cv;
  cv.h = __float2bfloat16(f);
  return cv.u;
}

// ---------------- fused weight prep (all 6 transforms in one launch) --------
__global__ __launch_bounds__(256) void prep_all(
    const float* __restrict__ t1w, const float* __restrict__ t3w,
    const float* __restrict__ t4w, const float* __restrict__ t2w,
    const float* __restrict__ w2, const float* __restrict__ w3,
    ushort* __restrict__ wp1, ushort* __restrict__ wp3,
    ushort* __restrict__ wp4, ushort* __restrict__ wp2,
    _Float16* __restrict__ w2h, _Float16* __restrict__ w2l,
    _Float16* __restrict__ w3h, _Float16* __restrict__ w3l) {
  const int b = blockIdx.x, t = threadIdx.x;
  if (b < 1024) {
    int idx = b * 256 + t;
    int ci = idx & 127, co = (idx >> 7) & 127, tap = idx >> 14;
    wp1[idx] = f2bf(t1w[((size_t)ci * 128 + co) * 16 + (15 - tap)]);
  } else if (b < 2624) {
    int idx = (b - 1024) * 256 + t;
    int ci = idx & 127, co = (idx >> 7) & 127, tap = idx >> 14;
    wp3[idx] = f2bf(t3w[((size_t)ci * 128 + co) * 25 + (24 - tap)]);
  } else if (b < 4224) {
    int idx = (b - 2624) * 256 + t;
    int ci = idx & 127, co = (idx >> 7) & 127, tap = idx >> 14;
    wp4[idx] = f2bf(t4w[((size_t)ci * 128 + co) * 25 + (24 - tap)]);
  } else if (b < 5248) {
    int idx = (b - 4224) * 256 + t;
    int ci = idx & 127, co = (idx >> 7) & 127;
    int tap = (idx >> 14) & 3, pp = idx >> 16;
    int u = tap >> 1, v = tap & 1, py = pp >> 1, px = pp & 1;
    wp2[idx] = f2bf(
        t2w[(((size_t)ci * 128 + co) * 4 + (py + 2 * u)) * 4 + (px + 2 * v)]);
  } else if (b < 6848) {
    int idx = (b - 5248) * 256 + t;
    int ci = idx & 127, co = (idx >> 7) & 127, tap = idx >> 14;
    float v = w2[((size_t)co * 128 + ci) * 25 + tap];
    _Float16 h = (_Float16)v;
    w2h[idx] = h;
    w2l[idx] = (_Float16)(v - (float)h);
  } else {
    int idx = (b - 6848) * 256 + t;
    int ci = idx & 127, co = (idx >> 7) & 127, tap = idx >> 14;
    float v = w3[((size_t)co * 128 + ci) * 25 + tap];
    _Float16 h = (_Float16)v;
    w3h[idx] = h;
    w3l[idx] = (_Float16)(v - (float)h);
  }
}

// ------- conv1: (B,1,28,28) -> NHWC hi/lo (B,576,128), 5x5, pad0, ReLU ------
__global__ __launch_bounds__(256) void conv1_kernel(
    const float* __restrict__ x, const float* __restrict__ w,
    const float* __restrict__ b, _Float16* __restrict__ oh,
    _Float16* __restrict__ ol) {
  const int n = blockIdx.x;
  __shared__ float xl[784];
  __shared__ float wl[128 * 25];
  __shared__ float bl[128];
  const int t = threadIdx.x;
  for (int e = t; e < 784; e += 256) xl[e] = x[n * 784 + e];
  for (int e = t; e < 3200; e += 256) wl[e] = w[e];
  if (t < 128) bl[t] = b[t];
  __syncthreads();
  const size_t nb = (size_t)n * 73728;
  for (int idx = t; idx < 73728; idx += 256) {
    int co = idx & 127, p = idx >> 7;
    int y = p / 24, xx = p % 24;
    float acc = bl[co];
    const float* wc = &wl[co * 25];
#pragma unroll
    for (int ky = 0; ky < 5; ky++)
#pragma unroll
      for (int kx = 0; kx < 5; kx++)
        acc += xl[(y + ky) * 28 + xx + kx] * wc[ky * 5 + kx];
    float v = fmaxf(acc, 0.f);
    _Float16 h = (_Float16)v;
    oh[nb + idx] = h;
    ol[nb + idx] = (_Float16)(v - (float)h);
  }
}

// ---------------- split-fp16 MFMA conv + bias(+relu) + 2x2 maxpool ----------
// R13 generic template (conv2 + conv3). Linear LDS slot; PWX padded row.
template <int IW, int K, int PAD, int TR, bool RELU, bool OUT_F32, int PWX>
__global__ __launch_bounds__(256, 3) void conv_mfma_pool(
    const _Float16* __restrict__ inh, const _Float16* __restrict__ inl,
    const _Float16* __restrict__ wph, const _Float16* __restrict__ wpl,
    const float* __restrict__ bias, _Float16* __restrict__ outh,
    _Float16* __restrict__ outl, float* __restrict__ outf) {
  constexpr int IH = IW, OW = IW, OH = IW;
  constexpr int PW = PWX;
  constexpr int SROWS = TR + K - 1;
  constexpr int S = SROWS * PW;
  constexpr int NPOS = TR * OW;
  constexpr int NCH = NPOS / 16;
  constexpr int SCRP = NPOS + 1;
  constexpr int K2 = K * K;
  constexpr int PITCH = 40;
  constexpr int LIN_ELT = S * PITCH;
  constexpr int LIN_BYTES = 2 * LIN_ELT * 2;
  constexpr int SCR_BYTES = 64 * SCRP * 4;
  constexpr int SMEM_BYTES = LIN_BYTES > SCR_BYTES ? LIN_BYTES : SCR_BYTES;
  static_assert(NPOS % 16 == 0, "");
  static_assert(TR % 2 == 0 && OW % 2 == 0, "");
  static_assert(PW >= OW + K - 1, "");
  __shared__ __align__(16) char smem[SMEM_BYTES];
  _Float16* linh = (_Float16*)smem;
  _Float16* linl = linh + LIN_ELT;
  const int n = blockIdx.x;
  const int r0 = blockIdx.y * TR;
  const int t = threadIdx.x;
  const int wv = t >> 6;
  const int lane = t & 63;
  const int nn = lane & 15;
  const int q = lane >> 4;
  f32x4 acc0[NCH], acc1[NCH];
  int boff[NCH];
#pragma unroll
  for (int c = 0; c < NCH; c++) {
    acc0[c] = f32x4{0.f, 0.f, 0.f, 0.f};
    acc1[c] = f32x4{0.f, 0.f, 0.f, 0.f};
    int p = c * 16 + nn;
    boff[c] = ((p / OW) * PW + (p % OW)) * PITCH + q * 8;
  }
  const int rowA = wv * 16 + nn;
  const int rowB = (wv + 4) * 16 + nn;
  for (int cb = 0; cb < 4; cb++) {
    const int ci0 = cb * 32;
    __syncthreads();
    for (int e = t; e < S * 4; e += 256) {
      int sp = e >> 2, j = e & 3;
      int r = sp / PW, c = sp - r * PW;
      int ir = r0 + r - PAD, ic = c - PAD;
      f16x8 vh = {0, 0, 0, 0, 0, 0, 0, 0};
      f16x8 vl = {0, 0, 0, 0, 0, 0, 0, 0};
      if (ir >= 0 && ir < IH && ic >= 0 && ic < IW) {
        size_t g = ((size_t)n * (IH * IW) + ir * IW + ic) * 128 + ci0 + j * 8;
        vh = *(const f16x8*)&inh[g];
        vl = *(const f16x8*)&inl[g];
      }
      int st = sp * PITCH + j * 8;
      *(f16x8*)&linh[st] = vh;
      *(f16x8*)&linl[st] = vl;
    }
    __syncthreads();
    const size_t gA = (size_t)rowA * 128 + ci0 + q * 8;
    const size_t gB = (size_t)rowB * 128 + ci0 + q * 8;
    f16x8 cah0 = *(const f16x8*)&wph[gA];
    f16x8 cal0 = *(const f16x8*)&wpl[gA];
    f16x8 cah1 = *(const f16x8*)&wph[gB];
    f16x8 cal1 = *(const f16x8*)&wpl[gB];
    for (int tap = 0; tap < K2; tap++) {
      f16x8 nah0 = cah0, nal0 = cal0, nah1 = cah1, nal1 = cal1;
      if (tap + 1 < K2) {
        size_t oA = gA + (size_t)(tap + 1) * 16384;
        size_t oB = gB + (size_t)(tap + 1) * 16384;
        nah0 = *(const f16x8*)&wph[oA];
        nal0 = *(const f16x8*)&wpl[oA];
        nah1 = *(const f16x8*)&wph[oB];
        nal1 = *(const f16x8*)&wpl[oB];
      }
      const int ky = tap / K, kx = tap - ky * K;
      const int tp = (ky * PW + kx) * PITCH;
#pragma unroll
      for (int c = 0; c < NCH; c++) {
        int off = boff[c] + tp;
        f16x8 bh = *(const f16x8*)&linh[off];
        f16x8 bl = *(const f16x8*)&linl[off];
        acc0[c] =
            __builtin_amdgcn_mfma_f32_16x16x32_f16(cah0, bh, acc0[c], 0, 0, 0);
        acc0[c] =
            __builtin_amdgcn_mfma_f32_16x16x32_f16(cah0, bl, acc0[c], 0, 0, 0);
        acc0[c] =
            __builtin_amdgcn_mfma_f32_16x16x32_f16(cal0, bh, acc0[c], 0, 0, 0);
        acc1[c] =
            __builtin_amdgcn_mfma_f32_16x16x32_f16(cah1, bh, acc1[c], 0, 0, 0);
        acc1[c] =
            __builtin_amdgcn_mfma_f32_16x16x32_f16(cah1, bl, acc1[c], 0, 0, 0);
        acc1[c] =
            __builtin_amdgcn_mfma_f32_16x16x32_f16(cal1, bh, acc1[c], 0, 0, 0);
      }
      cah0 = nah0; cal0 = nal0; cah1 = nah1; cal1 = nal1;
    }
  }
  __syncthreads();
  float* scr = (float*)smem + wv * 16 * SCRP;
#pragma unroll
  for (int j = 0; j < 2; j++) {
    const int cot = (j ? wv + 4 : wv) * 16;
#pragma unroll
    for (int c = 0; c < NCH; c++) {
      f32x4 a = j ? acc1[c] : acc0[c];
#pragma unroll
      for (int r = 0; r < 4; r++) {
        float v = a[r] + bias[cot + q * 4 + r];
        if (RELU) v = fmaxf(v, 0.f);
        scr[(q * 4 + r) * SCRP + c * 16 + nn] = v;
      }
    }
    __syncthreads();
    for (int e = lane; e < 16 * (TR / 2) * (OW / 2); e += 64) {
      int co_l = e & 15;
      int rem = e >> 4;
      int pr = rem / (OW / 2), pc = rem - pr * (OW / 2);
      const float* s = scr + co_l * SCRP;
      int lp = (2 * pr) * OW + 2 * pc;
      float m =
          fmaxf(fmaxf(s[lp], s[lp + 1]), fmaxf(s[lp + OW], s[lp + OW + 1]));
      int sp_out = (r0 / 2 + pr) * (OW / 2) + pc;
      size_t go =
          ((size_t)n * ((OH / 2) * (OW / 2)) + sp_out) * 128 + cot + co_l;
      if (OUT_F32) {
        outf[go] = m;
      } else {
        _Float16 h = (_Float16)m;
        outh[go] = h;
        outl[go] = (_Float16)(m - (float)h);
      }
    }
    __syncthreads();
  }
}

// ---------------- VQ on NHWC z: argmax(d2), gather + fused dict/enc loss ----
__global__ __launch_bounds__(256) void vq_kernel(
    const float* __restrict__ z, const float* __restrict__ dict,
    float* __restrict__ val, ushort* __restrict__ val_bf,
    float* __restrict__ out_idx, float* __restrict__ out) {
  const int n = blockIdx.x;
  __shared__ float zl[36 * 128];
  __shared__ float d2[36 * 129];
  __shared__ float w2n[128];
  __shared__ int bk[36];
  __shared__ float red[256];
  const int t = threadIdx.x;
  const float* zn = z + (size_t)n * 4608;
  for (int e = t; e < 4608; e += 256) zl[e] = zn[e];
  if (t < 128) {
    float s = 0.f;
    const float* wr = dict + t * 128;
    for (int c = 0; c < 128; c++) s += wr[c] * wr[c];
    w2n[t] = s;
  }
  __syncthreads();
  const int k = t & 127, pg = t >> 7;
  float dot[18];
#pragma unroll
  for (int i = 0; i < 18; i++) dot[i] = 0.f;
  const float* wr = dict + k * 128;
  for (int c = 0; c < 128; c++) {
    float wv = wr[c];
#pragma unroll
    for (int i = 0; i < 18; i++) dot[i] += zl[(pg * 18 + i) * 128 + c] * wv;
  }
  float wn = w2n[k];
#pragma unroll
  for (int i = 0; i < 18; i++) d2[(pg * 18 + i) * 129 + k] = wn - 2.f * dot[i];
  __syncthreads();
  if (t < 36) {
    const float* dr = &d2[t * 129];
    float best = dr[0];
    int bi = 0;
    for (int kk = 1; kk < 128; kk++) {
      float v = dr[kk];
      if (v > best) { best = v; bi = kk; }  // strict >: first max (argmax tie)
    }
    bk[t] = bi;
    out_idx[n * 36 + t] = (float)bi;
  }
  __syncthreads();
  float* vn = val + (size_t)n * 4608;
  ushort* vbn = val_bf + (size_t)n * 4608;
  float lsum = 0.f;
  for (int e = t; e < 4608; e += 256) {
    int c = e & 127, p = e >> 7;
    float v = dict[bk[p] * 128 + c];
    vn[e] = v;
    vbn[e] = f2bf(v);
    float d = v - zl[e];
    lsum += d * d;
  }
  red[t] = lsum;
  __syncthreads();
  for (int off = 128; off > 0; off >>= 1) {
    if (t < off) red[t] += red[t + off];
    __syncthreads();
  }
  if (t == 0) {
    atomicAdd(out + 1, red[0] * (5.f / 1179648.f));
    atomicAdd(out + 2, red[0] * (1.25f / 1179648.f));
  }
}

// ---- bf16 MFMA deconv (s1), NHWC bf16 io, wave-dedup, LDS dbuf, opt. mu ----
// R18: R15's dedup structure (correctness-proven) at small TR so registers
// fit: wave = (tile-half pairid, co-half cohalf); 64 co per wave (4 A-frags);
// 4 MFMAs per B ds_read_b128 -> B-reads halved vs 2-co-group scheme.
template <int IH, int IW, int OH, int OW, int K, int TR, bool MU_FUSE, int PWX>
__global__ __launch_bounds__(256, 2) void deconv_mfma(
    const ushort* __restrict__ in, const ushort* __restrict__ wprep,
    const float* __restrict__ bias, const float* __restrict__ mw,
    void* __restrict__ outp) {
  constexpr int PAD = K - 1;
  constexpr int PW = PWX;
  constexpr int K2 = K * K;
  constexpr int SROWS = TR + K - 1;
  constexpr int S = SROWS * PW;
  constexpr int NPOS = TR * OW;
  constexpr int NCH = (NPOS + 15) / 16;
  constexpr int NT0 = (NCH + 1) / 2;  // tiles for pair 0 (waves 0,1)
  constexpr int NT1 = NCH - NT0;      // tiles for pair 1 (waves 2,3)
  constexpr int PITCH = 40;
  constexpr int LIN_ELT = S * PITCH;
  constexpr int NSTG = (S * 4 + 255) / 256;
  static_assert(PW >= OW + K - 1, "");
  __shared__ __align__(16) ushort lin[2][LIN_ELT];
  const int n = blockIdx.x;
  const int r0 = blockIdx.y * TR;
  const int t = threadIdx.x;
  const int wv = t >> 6;
  const int lane = t & 63;
  const int nn = lane & 15;
  const int q = lane >> 4;
  const int pairid = wv >> 1;  // 0: tiles [0,NT0); 1: tiles [NT0,NCH)
  const int cohalf = wv & 1;   // 0: co 0-63; 1: co 64-127
  f32x4 acc[NT0][4];
  int boff[NT0];
#pragma unroll
  for (int tL = 0; tL < NT0; tL++) {
#pragma unroll
    for (int g = 0; g < 4; g++) acc[tL][g] = f32x4{0.f, 0.f, 0.f, 0.f};
    int tg = pairid * NT0 + tL;
    if (tg > NCH - 1) tg = NCH - 1;
    int p = tg * 16 + nn;
    int pc = p < NPOS ? p : NPOS - 1;
    boff[tL] = ((pc / OW) * PW + (pc % OW)) * PITCH + q * 8;
  }
  s16x8 stg[NSTG];
  auto load_stage = [&](int ci0) {
#pragma unroll
    for (int i = 0; i < NSTG; i++) {
      int e = t + i * 256;
      s16x8 v = {0, 0, 0, 0, 0, 0, 0, 0};
      if (e < S * 4) {
        int sp = e >> 2, j = e & 3;
        int rr = sp / PW, cc = sp - rr * PW;
        int ir = r0 + rr - PAD, ic = cc - PAD;
        if (ir >= 0 && ir < IH && ic >= 0 && ic < IW)
          v = *(const s16x8*)&in[((size_t)n * (IH * IW) + ir * IW + ic) * 128 +
                                 ci0 + j * 8];
      }
      stg[i] = v;
    }
  };
  auto store_stage = [&](int bsel) {
#pragma unroll
    for (int i = 0; i < NSTG; i++) {
      int e = t + i * 256;
      if (e < S * 4) {
        int sp = e >> 2, j = e & 3;
        *(s16x8*)&lin[bsel][sp * PITCH + j * 8] = stg[i];
      }
    }
  };

  load_stage(0);
  store_stage(0);
  __syncthreads();
  for (int cb = 0; cb < 4; cb++) {
    const int ci0 = cb * 32;
    if (cb < 3) load_stage(ci0 + 32);
    const ushort* L = lin[cb & 1];
    size_t gA[4];
#pragma unroll
    for (int g = 0; g < 4; g++)
      gA[g] = (size_t)(cohalf * 64 + g * 16 + nn) * 128 + ci0 + q * 8;
    s16x8 ca[4];
#pragma unroll
    for (int g = 0; g < 4; g++) ca[g] = *(const s16x8*)&wprep[gA[g]];
    for (int tap = 0; tap < K2; tap++) {
      s16x8 na[4];
#pragma unroll
      for (int g = 0; g < 4; g++) na[g] = ca[g];
      if (tap + 1 < K2) {
        const size_t to = (size_t)(tap + 1) * 16384;
#pragma unroll
        for (int g = 0; g < 4; g++)
          na[g] = *(const s16x8*)&wprep[gA[g] + to];
      }
      const int ky = tap / K, kx = tap - ky * K;
      const int tp = (ky * PW + kx) * PITCH;
#pragma unroll
      for (int tL = 0; tL < NT0; tL++) {
        if (pairid == 0 || tL < NT1) {
          s16x8 b = *(const s16x8*)&L[boff[tL] + tp];
#pragma unroll
          for (int g = 0; g < 4; g++)
            acc[tL][g] = __builtin_amdgcn_mfma_f32_16x16x32_bf16(ca[g], b,
                                                                acc[tL][g], 0,
                                                                0, 0);
        }
      }
#pragma unroll
      for (int g = 0; g < 4; g++) ca[g] = na[g];
    }
    if (cb < 3) {
      store_stage((cb + 1) & 1);
      __syncthreads();
    }
  }
  float bav[4][4];
#pragma unroll
  for (int g = 0; g < 4; g++)
#pragma unroll
    for (int r = 0; r < 4; r++)
      bav[g][r] = bias[cohalf * 64 + g * 16 + q * 4 + r];
  if (!MU_FUSE) {
    ushort* out = (ushort*)outp;
#pragma unroll
    for (int tL = 0; tL < NT0; tL++) {
      if (pairid == 0 || tL < NT1) {
        int tg = pairid * NT0 + tL;
        int p = tg * 16 + nn;
        if (p < NPOS) {
          size_t go =
              ((size_t)n * (OH * OW) + r0 * OW + p) * 128 + cohalf * 64;
#pragma unroll
          for (int g = 0; g < 4; g++) {
            s16x4 pk;
#pragma unroll
            for (int r = 0; r < 4; r++)
              pk[r] = (short)f2bf(fmaxf(acc[tL][g][r] + bav[g][r], 0.f));
            *(s16x4*)&out[go + g * 16 + q * 4] = pk;
          }
        }
      }
    }
  } else {
    float* out = (float*)outp;
    float mwv[4][4];
#pragma unroll
    for (int g = 0; g < 4; g++)
#pragma unroll
      for (int r = 0; r < 4; r++)
        mwv[g][r] = mw[cohalf * 64 + g * 16 + q * 4 + r];
#pragma unroll
    for (int tL = 0; tL < NT0; tL++) {
      if (pairid == 0 || tL < NT1) {
        int tg = pairid * NT0 + tL;
        int p = tg * 16 + nn;
        float s = 0.f;
#pragma unroll
        for (int g = 0; g < 4; g++)
#pragma unroll
          for (int r = 0; r < 4; r++)
            s += fmaxf(acc[tL][g][r] + bav[g][r], 0.f) * mwv[g][r];
        s += __shfl_xor(s, 16);
        s += __shfl_xor(s, 32);
        if (q == 0 && p < NPOS)
          atomicAdd(&out[(size_t)n * (OH * OW) + r0 * OW + p], s);
      }
    }
  }
}

// ---------------- t2: k4 s2 deconv via parity decomposition, bf16 NHWC ------
__global__ __launch_bounds__(256, 3) void deconv_s2_mfma(
    const ushort* __restrict__ in, const ushort* __restrict__ wp2,
    const float* __restrict__ bias, ushort* __restrict__ out) {
  constexpr int NCH = 7;
  constexpr int PITCH = 40;
  constexpr int PW = 18;
  constexpr int S = 11 * PW;
  const int n = blockIdx.x;
  const int pp = blockIdx.y;
  const int py = pp >> 1, px = pp & 1;
  __shared__ __align__(16) ushort lin[S * PITCH];
  const int t = threadIdx.x;
  const int wv = t >> 6;
  const int lane = t & 63;
  const int nn = lane & 15;
  const int q = lane >> 4;
  f32x4 acc0[NCH], acc1[NCH];
  int boff[NCH];
#pragma unroll
  for (int c = 0; c < NCH; c++) {
    acc0[c] = f32x4{0.f, 0.f, 0.f, 0.f};
    acc1[c] = f32x4{0.f, 0.f, 0.f, 0.f};
    int p = c * 16 + nn;
    int pc = p < 100 ? p : 99;
    boff[c] = ((pc / 10) * PW + (pc % 10)) * PITCH + q * 8;
  }
  const int toffs[4] = {PW + 1, PW, 1, 0};
  for (int cb = 0; cb < 4; cb++) {
    const int ci0 = cb * 32;
    __syncthreads();
    for (int e = t; e < S * 4; e += 256) {
      int sp = e >> 2, j = e & 3;
      int r = sp / PW, c2 = sp - r * PW;
      int ir = r - 1, ic = c2 - 1;
      s16x8 v = {0, 0, 0, 0, 0, 0, 0, 0};
      if (ir >= 0 && ir < 9 && ic >= 0 && ic < 9)
        v = *(const s16x8*)&in[((size_t)n * 81 + ir * 9 + ic) * 128 + ci0 +
                               j * 8];
      *(s16x8*)&lin[sp * PITCH + j * 8] = v;
    }
    __syncthreads();
    const size_t gA =
        ((size_t)(pp * 4) * 128 + wv * 16 + nn) * 128 + ci0 + q * 8;
    const size_t gB =
        ((size_t)(pp * 4) * 128 + (wv + 4) * 16 + nn) * 128 + ci0 + q * 8;
    s16x8 ca0 = *(const s16x8*)&wp2[gA];
    s16x8 ca1 = *(const s16x8*)&wp2[gB];
    for (int tap = 0; tap < 4; tap++) {
      s16x8 na0 = ca0, na1 = ca1;
      if (tap + 1 < 4) {
        na0 = *(const s16x8*)&wp2[gA + (size_t)(tap + 1) * 16384];
        na1 = *(const s16x8*)&wp2[gB + (size_t)(tap + 1) * 16384];
      }
      const int tp = toffs[tap] * PITCH;
#pragma unroll
      for (int c = 0; c < NCH; c++) {
        s16x8 b = *(const s16x8*)&lin[boff[c] + tp];
        acc0[c] =
            __builtin_amdgcn_mfma_f32_16x16x32_bf16(ca0, b, acc0[c], 0, 0, 0);
        acc1[c] =
            __builtin_amdgcn_mfma_f32_16x16x32_bf16(ca1, b, acc1[c], 0, 0, 0);
      }
      ca0 = na0; ca1 = na1;
    }
  }
  const int co_a = wv * 16 + q * 4;
  const int co_b = (wv + 4) * 16 + q * 4;
#pragma unroll
  for (int c = 0; c < NCH; c++) {
    int p = c * 16 + nn;
    if (p < 100) {
      int oy = 2 * (p / 10) + py, ox = 2 * (p % 10) + px;
      size_t go = ((size_t)n * 400 + oy * 20 + ox) * 128;
      s16x4 pa, pb;
#pragma unroll
      for (int r = 0; r < 4; r++) {
        pa[r] = (short)f2bf(fmaxf(acc0[c][r] + bias[co_a + r], 0.f));
        pb[r] = (short)f2bf(fmaxf(acc1[c][r] + bias[co_b + r], 0.f));
      }
      *(s16x4*)&out[go + co_a] = pa;
      *(s16x4*)&out[go + co_b] = pb;
    }
  }
}

// ---------------- rec loss only ([0,784)); dict/enc fused into vq ----------
__global__ __launch_bounds__(256) void loss_kernel(
    const float* __restrict__ mu, const float* __restrict__ mb,
    const float* __restrict__ x, float* __restrict__ out) {
  const int b = blockIdx.x, t = threadIdx.x;
  __shared__ float red[256];
  int i = b * 256 + t;
  float d = mu[i] + mb[0] - x[i];
  red[t] = d * d;
  __syncthreads();
  for (int off = 128; off > 0; off >>= 1) {
    if (t < off) red[t] += red[t + off];
    __syncthreads();
  }
  if (t == 0) atomicAdd(out, red[0] * (1.0f / 200704.f));
}

// ---------------------------------------------------------------------------
extern "C" void kernel_launch(void* const* d_in, const int* in_sizes, int n_in,
                              void* d_out, int out_size, void* d_ws,
                              size_t ws_size, hipStream_t stream) {
  const float* x = (const float*)d_in[0];
  const float* w1 = (const float*)d_in[1];
  const float* b1 = (const float*)d_in[2];
  const float* w2 = (const float*)d_in[3];
  const float* b2 = (const float*)d_in[4];
  const float* w3 = (const float*)d_in[5];
  const float* b3 = (const float*)d_in[6];
  const float* t1w = (const float*)d_in[7];
  const float* t1b = (const float*)d_in[8];
  const float* t2w = (const float*)d_in[9];
  const float* t2b = (const float*)d_in[10];
  const float* t3w = (const float*)d_in[11];
  const float* t3b = (const float*)d_in[12];
  const float* t4w = (const float*)d_in[13];
  const float* t4b = (const float*)d_in[14];
  const float* mw = (const float*)d_in[15];
  const float* mb = (const float*)d_in[16];
  const float* dictw = (const float*)d_in[17];
  float* out = (float*)d_out;

  float* p = (float*)d_ws;
  _Float16* h1h = (_Float16*)p; p += 9437184;
  _Float16* h1l = (_Float16*)p; p += 9437184;
  _Float16* p1h = (_Float16*)p; p += 2359296;
  _Float16* p1l = (_Float16*)p; p += 2359296;
  float* z = p; p += 1179648;
  float* val = p; p += 1179648;
  ushort* val_bf = (ushort*)p; p += 589824;
  float* mu = p; p += 200704;
  ushort* wp1 = (ushort*)p; p += 131072;
  ushort* wp3 = (ushort*)p; p += 204800;
  ushort* wp4 = (ushort*)p; p += 204800;
  ushort* wp2 = (ushort*)p; p += 131072;
  _Float16* w2h = (_Float16*)p; p += 204800;
  _Float16* w2l = (_Float16*)p; p += 204800;
  _Float16* w3h = (_Float16*)p; p += 204800;
  _Float16* w3l = (_Float16*)p; p += 204800;
  // aliases (dead buffers reused):
  ushort* f1 = (ushort*)p1h;  // (256,81,128) bf16
  ushort* f2 = (ushort*)h1l;  // (256,400,128) bf16
  ushort* f3 = (ushort*)h1h;  // (256,576,128) bf16

  hipMemsetAsync(d_out, 0, 4 * sizeof(float), stream);
  hipMemsetAsync(mu, 0, 200704 * sizeof(float), stream);

  prep_all<<<8448, 256, 0, stream>>>(t1w, t3w, t4w, t2w, w2, w3, wp1, wp3, wp4,
                                     wp2, w2h, w2l, w3h, w3l);

  conv1_kernel<<<B_, 256, 0, stream>>>(x, w1, b1, h1h, h1l);
  // conv2: 24x24 K5 pad2 relu + pool -> p1 hi/lo NHWC (12x12), TR=6, PW=28
  conv_mfma_pool<24, 5, 2, 6, true, false, 28>
      <<<dim3(B_, 4), 256, 0, stream>>>(h1h, h1l, w2h, w2l, b2, p1h, p1l,
                                        nullptr);
  // conv3: 12x12 K5 pad2 + pool -> z f32 NHWC (6x6), TR=4, PW=20 (OW+8)
  conv_mfma_pool<12, 5, 2, 4, false, true, 20>
      <<<dim3(B_, 3), 256, 0, stream>>>(p1h, p1l, w3h, w3l, b3, nullptr,
                                        nullptr, z);
  vq_kernel<<<B_, 256, 0, stream>>>(z, dictw, val, val_bf, out + 4, out);
  // t1: 6->9, K4 s1, relu  [bf16 NHWC, dedup TR=3, y=3], PW=17 (OW+8)
  deconv_mfma<6, 6, 9, 9, 4, 3, false, 17>
      <<<dim3(B_, 3), 256, 0, stream>>>(val_bf, wp1, t1b, nullptr, f1);
  // t2: 9->20, K4 s2, relu  [bf16 NHWC, parity decomposition], PW=18
  deconv_s2_mfma<<<dim3(B_, 4), 256, 0, stream>>>(f1, wp2, t2b, f2);
  // t3: 20->24, K5 s1, relu  [bf16 NHWC, dedup TR=4, y=6, NT 3/3], PW=28
  deconv_mfma<20, 20, 24, 24, 5, 4, false, 28>
      <<<dim3(B_, 6), 256, 0, stream>>>(f2, wp3, t3b, nullptr, f3);
  // t4: 24->28, K5 s1, relu + fused 1x1 mu [bf16 NHWC, dedup TR=4, y=7], PW=36
  deconv_mfma<24, 24, 28, 28, 5, 4, true, 36>
      <<<dim3(B_, 7), 256, 0, stream>>>(f3, wp4, t4b, mw, mu);
  loss_kernel<<<784, 256, 0, stream>>>(mu, mb, x, out);
}

// Round 9
// 881.351 us; speedup vs baseline: 1.4658x; 1.4658x over previous
//
#include <hip/hip_runtime.h>
#include <hip/hip_bf16.h>

// ---------------------------------------------------------------------------
// VQ-VAE forward. R19: revert to R17 (best, 897us) + float4 loss kernel.
// Dedup post-mortem (R14/R15/R16/R18, all failed): any wave structure
// holding 4 double-buffered A-fragments collapses the pre-RA scheduler
// (VGPR squeezed to 84-128, MfmaUtil 58->17-37%) regardless of occupancy
// attrs, tile size, or guard-freeness. At the working 2-A-frag structure,
// deconv B-reads (NCH x 4 waves per cb-tap) are invariant — t4 sits at
// max(MFMA 79us, LDS-BW 69us)+barriers ~= 150us, near its structural
// ceiling. conv2 at 59% MfmaUtil is at its LDS||MFMA overlap limit.
// KEPT: R13 linear LDS slot + PW padding; vq-fused dict/enc losses;
// rec-only loss kernel (now float4, 196 blocks).
// ---------------------------------------------------------------------------

#define B_ 256

typedef __attribute__((ext_vector_type(8))) short s16x8;
typedef __attribute__((ext_vector_type(4))) short s16x4;
typedef __attribute__((ext_vector_type(8))) _Float16 f16x8;
typedef __attribute__((ext_vector_type(4))) float f32x4;

__device__ inline ushort f2bf(float f) {
  union { __hip_bfloat16 h; ushort u; } cv;
  cv.h = __float2bfloat16(f);
  return cv.u;
}

// ---------------- fused weight prep (all 6 transforms in one launch) --------
__global__ __launch_bounds__(256) void prep_all(
    const float* __restrict__ t1w, const float* __restrict__ t3w,
    const float* __restrict__ t4w, const float* __restrict__ t2w,
    const float* __restrict__ w2, const float* __restrict__ w3,
    ushort* __restrict__ wp1, ushort* __restrict__ wp3,
    ushort* __restrict__ wp4, ushort* __restrict__ wp2,
    _Float16* __restrict__ w2h, _Float16* __restrict__ w2l,
    _Float16* __restrict__ w3h, _Float16* __restrict__ w3l) {
  const int b = blockIdx.x, t = threadIdx.x;
  if (b < 1024) {
    int idx = b * 256 + t;
    int ci = idx & 127, co = (idx >> 7) & 127, tap = idx >> 14;
    wp1[idx] = f2bf(t1w[((size_t)ci * 128 + co) * 16 + (15 - tap)]);
  } else if (b < 2624) {
    int idx = (b - 1024) * 256 + t;
    int ci = idx & 127, co = (idx >> 7) & 127, tap = idx >> 14;
    wp3[idx] = f2bf(t3w[((size_t)ci * 128 + co) * 25 + (24 - tap)]);
  } else if (b < 4224) {
    int idx = (b - 2624) * 256 + t;
    int ci = idx & 127, co = (idx >> 7) & 127, tap = idx >> 14;
    wp4[idx] = f2bf(t4w[((size_t)ci * 128 + co) * 25 + (24 - tap)]);
  } else if (b < 5248) {
    int idx = (b - 4224) * 256 + t;
    int ci = idx & 127, co = (idx >> 7) & 127;
    int tap = (idx >> 14) & 3, pp = idx >> 16;
    int u = tap >> 1, v = tap & 1, py = pp >> 1, px = pp & 1;
    wp2[idx] = f2bf(
        t2w[(((size_t)ci * 128 + co) * 4 + (py + 2 * u)) * 4 + (px + 2 * v)]);
  } else if (b < 6848) {
    int idx = (b - 5248) * 256 + t;
    int ci = idx & 127, co = (idx >> 7) & 127, tap = idx >> 14;
    float v = w2[((size_t)co * 128 + ci) * 25 + tap];
    _Float16 h = (_Float16)v;
    w2h[idx] = h;
    w2l[idx] = (_Float16)(v - (float)h);
  } else {
    int idx = (b - 6848) * 256 + t;
    int ci = idx & 127, co = (idx >> 7) & 127, tap = idx >> 14;
    float v = w3[((size_t)co * 128 + ci) * 25 + tap];
    _Float16 h = (_Float16)v;
    w3h[idx] = h;
    w3l[idx] = (_Float16)(v - (float)h);
  }
}

// ------- conv1: (B,1,28,28) -> NHWC hi/lo (B,576,128), 5x5, pad0, ReLU ------
__global__ __launch_bounds__(256) void conv1_kernel(
    const float* __restrict__ x, const float* __restrict__ w,
    const float* __restrict__ b, _Float16* __restrict__ oh,
    _Float16* __restrict__ ol) {
  const int n = blockIdx.x;
  __shared__ float xl[784];
  __shared__ float wl[128 * 25];
  __shared__ float bl[128];
  const int t = threadIdx.x;
  for (int e = t; e < 784; e += 256) xl[e] = x[n * 784 + e];
  for (int e = t; e < 3200; e += 256) wl[e] = w[e];
  if (t < 128) bl[t] = b[t];
  __syncthreads();
  const size_t nb = (size_t)n * 73728;
  for (int idx = t; idx < 73728; idx += 256) {
    int co = idx & 127, p = idx >> 7;
    int y = p / 24, xx = p % 24;
    float acc = bl[co];
    const float* wc = &wl[co * 25];
#pragma unroll
    for (int ky = 0; ky < 5; ky++)
#pragma unroll
      for (int kx = 0; kx < 5; kx++)
        acc += xl[(y + ky) * 28 + xx + kx] * wc[ky * 5 + kx];
    float v = fmaxf(acc, 0.f);
    _Float16 h = (_Float16)v;
    oh[nb + idx] = h;
    ol[nb + idx] = (_Float16)(v - (float)h);
  }
}

// ---------------- split-fp16 MFMA conv + bias(+relu) + 2x2 maxpool ----------
// R13 generic template (conv2 + conv3). Linear LDS slot; PWX padded row.
template <int IW, int K, int PAD, int TR, bool RELU, bool OUT_F32, int PWX>
__global__ __launch_bounds__(256, 3) void conv_mfma_pool(
    const _Float16* __restrict__ inh, const _Float16* __restrict__ inl,
    const _Float16* __restrict__ wph, const _Float16* __restrict__ wpl,
    const float* __restrict__ bias, _Float16* __restrict__ outh,
    _Float16* __restrict__ outl, float* __restrict__ outf) {
  constexpr int IH = IW, OW = IW, OH = IW;
  constexpr int PW = PWX;
  constexpr int SROWS = TR + K - 1;
  constexpr int S = SROWS * PW;
  constexpr int NPOS = TR * OW;
  constexpr int NCH = NPOS / 16;
  constexpr int SCRP = NPOS + 1;
  constexpr int K2 = K * K;
  constexpr int PITCH = 40;
  constexpr int LIN_ELT = S * PITCH;
  constexpr int LIN_BYTES = 2 * LIN_ELT * 2;
  constexpr int SCR_BYTES = 64 * SCRP * 4;
  constexpr int SMEM_BYTES = LIN_BYTES > SCR_BYTES ? LIN_BYTES : SCR_BYTES;
  static_assert(NPOS % 16 == 0, "");
  static_assert(TR % 2 == 0 && OW % 2 == 0, "");
  static_assert(PW >= OW + K - 1, "");
  __shared__ __align__(16) char smem[SMEM_BYTES];
  _Float16* linh = (_Float16*)smem;
  _Float16* linl = linh + LIN_ELT;
  const int n = blockIdx.x;
  const int r0 = blockIdx.y * TR;
  const int t = threadIdx.x;
  const int wv = t >> 6;
  const int lane = t & 63;
  const int nn = lane & 15;
  const int q = lane >> 4;
  f32x4 acc0[NCH], acc1[NCH];
  int boff[NCH];
#pragma unroll
  for (int c = 0; c < NCH; c++) {
    acc0[c] = f32x4{0.f, 0.f, 0.f, 0.f};
    acc1[c] = f32x4{0.f, 0.f, 0.f, 0.f};
    int p = c * 16 + nn;
    boff[c] = ((p / OW) * PW + (p % OW)) * PITCH + q * 8;
  }
  const int rowA = wv * 16 + nn;
  const int rowB = (wv + 4) * 16 + nn;
  for (int cb = 0; cb < 4; cb++) {
    const int ci0 = cb * 32;
    __syncthreads();
    for (int e = t; e < S * 4; e += 256) {
      int sp = e >> 2, j = e & 3;
      int r = sp / PW, c = sp - r * PW;
      int ir = r0 + r - PAD, ic = c - PAD;
      f16x8 vh = {0, 0, 0, 0, 0, 0, 0, 0};
      f16x8 vl = {0, 0, 0, 0, 0, 0, 0, 0};
      if (ir >= 0 && ir < IH && ic >= 0 && ic < IW) {
        size_t g = ((size_t)n * (IH * IW) + ir * IW + ic) * 128 + ci0 + j * 8;
        vh = *(const f16x8*)&inh[g];
        vl = *(const f16x8*)&inl[g];
      }
      int st = sp * PITCH + j * 8;
      *(f16x8*)&linh[st] = vh;
      *(f16x8*)&linl[st] = vl;
    }
    __syncthreads();
    const size_t gA = (size_t)rowA * 128 + ci0 + q * 8;
    const size_t gB = (size_t)rowB * 128 + ci0 + q * 8;
    f16x8 cah0 = *(const f16x8*)&wph[gA];
    f16x8 cal0 = *(const f16x8*)&wpl[gA];
    f16x8 cah1 = *(const f16x8*)&wph[gB];
    f16x8 cal1 = *(const f16x8*)&wpl[gB];
    for (int tap = 0; tap < K2; tap++) {
      f16x8 nah0 = cah0, nal0 = cal0, nah1 = cah1, nal1 = cal1;
      if (tap + 1 < K2) {
        size_t oA = gA + (size_t)(tap + 1) * 16384;
        size_t oB = gB + (size_t)(tap + 1) * 16384;
        nah0 = *(const f16x8*)&wph[oA];
        nal0 = *(const f16x8*)&wpl[oA];
        nah1 = *(const f16x8*)&wph[oB];
        nal1 = *(const f16x8*)&wpl[oB];
      }
      const int ky = tap / K, kx = tap - ky * K;
      const int tp = (ky * PW + kx) * PITCH;
#pragma unroll
      for (int c = 0; c < NCH; c++) {
        int off = boff[c] + tp;
        f16x8 bh = *(const f16x8*)&linh[off];
        f16x8 bl = *(const f16x8*)&linl[off];
        acc0[c] =
            __builtin_amdgcn_mfma_f32_16x16x32_f16(cah0, bh, acc0[c], 0, 0, 0);
        acc0[c] =
            __builtin_amdgcn_mfma_f32_16x16x32_f16(cah0, bl, acc0[c], 0, 0, 0);
        acc0[c] =
            __builtin_amdgcn_mfma_f32_16x16x32_f16(cal0, bh, acc0[c], 0, 0, 0);
        acc1[c] =
            __builtin_amdgcn_mfma_f32_16x16x32_f16(cah1, bh, acc1[c], 0, 0, 0);
        acc1[c] =
            __builtin_amdgcn_mfma_f32_16x16x32_f16(cah1, bl, acc1[c], 0, 0, 0);
        acc1[c] =
            __builtin_amdgcn_mfma_f32_16x16x32_f16(cal1, bh, acc1[c], 0, 0, 0);
      }
      cah0 = nah0; cal0 = nal0; cah1 = nah1; cal1 = nal1;
    }
  }
  __syncthreads();
  float* scr = (float*)smem + wv * 16 * SCRP;
#pragma unroll
  for (int j = 0; j < 2; j++) {
    const int cot = (j ? wv + 4 : wv) * 16;
#pragma unroll
    for (int c = 0; c < NCH; c++) {
      f32x4 a = j ? acc1[c] : acc0[c];
#pragma unroll
      for (int r = 0; r < 4; r++) {
        float v = a[r] + bias[cot + q * 4 + r];
        if (RELU) v = fmaxf(v, 0.f);
        scr[(q * 4 + r) * SCRP + c * 16 + nn] = v;
      }
    }
    __syncthreads();
    for (int e = lane; e < 16 * (TR / 2) * (OW / 2); e += 64) {
      int co_l = e & 15;
      int rem = e >> 4;
      int pr = rem / (OW / 2), pc = rem - pr * (OW / 2);
      const float* s = scr + co_l * SCRP;
      int lp = (2 * pr) * OW + 2 * pc;
      float m =
          fmaxf(fmaxf(s[lp], s[lp + 1]), fmaxf(s[lp + OW], s[lp + OW + 1]));
      int sp_out = (r0 / 2 + pr) * (OW / 2) + pc;
      size_t go =
          ((size_t)n * ((OH / 2) * (OW / 2)) + sp_out) * 128 + cot + co_l;
      if (OUT_F32) {
        outf[go] = m;
      } else {
        _Float16 h = (_Float16)m;
        outh[go] = h;
        outl[go] = (_Float16)(m - (float)h);
      }
    }
    __syncthreads();
  }
}

// ---------------- VQ on NHWC z: argmax(d2), gather + fused dict/enc loss ----
__global__ __launch_bounds__(256) void vq_kernel(
    const float* __restrict__ z, const float* __restrict__ dict,
    float* __restrict__ val, ushort* __restrict__ val_bf,
    float* __restrict__ out_idx, float* __restrict__ out) {
  const int n = blockIdx.x;
  __shared__ float zl[36 * 128];
  __shared__ float d2[36 * 129];
  __shared__ float w2n[128];
  __shared__ int bk[36];
  __shared__ float red[256];
  const int t = threadIdx.x;
  const float* zn = z + (size_t)n * 4608;
  for (int e = t; e < 4608; e += 256) zl[e] = zn[e];
  if (t < 128) {
    float s = 0.f;
    const float* wr = dict + t * 128;
    for (int c = 0; c < 128; c++) s += wr[c] * wr[c];
    w2n[t] = s;
  }
  __syncthreads();
  const int k = t & 127, pg = t >> 7;
  float dot[18];
#pragma unroll
  for (int i = 0; i < 18; i++) dot[i] = 0.f;
  const float* wr = dict + k * 128;
  for (int c = 0; c < 128; c++) {
    float wv = wr[c];
#pragma unroll
    for (int i = 0; i < 18; i++) dot[i] += zl[(pg * 18 + i) * 128 + c] * wv;
  }
  float wn = w2n[k];
#pragma unroll
  for (int i = 0; i < 18; i++) d2[(pg * 18 + i) * 129 + k] = wn - 2.f * dot[i];
  __syncthreads();
  if (t < 36) {
    const float* dr = &d2[t * 129];
    float best = dr[0];
    int bi = 0;
    for (int kk = 1; kk < 128; kk++) {
      float v = dr[kk];
      if (v > best) { best = v; bi = kk; }  // strict >: first max (argmax tie)
    }
    bk[t] = bi;
    out_idx[n * 36 + t] = (float)bi;
  }
  __syncthreads();
  float* vn = val + (size_t)n * 4608;
  ushort* vbn = val_bf + (size_t)n * 4608;
  float lsum = 0.f;
  for (int e = t; e < 4608; e += 256) {
    int c = e & 127, p = e >> 7;
    float v = dict[bk[p] * 128 + c];
    vn[e] = v;
    vbn[e] = f2bf(v);
    float d = v - zl[e];
    lsum += d * d;
  }
  red[t] = lsum;
  __syncthreads();
  for (int off = 128; off > 0; off >>= 1) {
    if (t < off) red[t] += red[t + off];
    __syncthreads();
  }
  if (t == 0) {
    atomicAdd(out + 1, red[0] * (5.f / 1179648.f));
    atomicAdd(out + 2, red[0] * (1.25f / 1179648.f));
  }
}

// ---- bf16 MFMA deconv (s1), NHWC bf16 io, LDS double-buffer, opt. mu -------
// R13 version (2 named A-frags — the only structure this compiler schedules
// well). PWX: padded staged-row width.
template <int IH, int IW, int OH, int OW, int K, int TR, bool MU_FUSE, int PWX>
__global__ __launch_bounds__(256, 2) void deconv_mfma(
    const ushort* __restrict__ in, const ushort* __restrict__ wprep,
    const float* __restrict__ bias, const float* __restrict__ mw,
    void* __restrict__ outp) {
  constexpr int PAD = K - 1;
  constexpr int PW = PWX;
  constexpr int K2 = K * K;
  constexpr int SROWS = TR + K - 1;
  constexpr int S = SROWS * PW;
  constexpr int NPOS = TR * OW;
  constexpr int NCH = (NPOS + 15) / 16;
  constexpr int PITCH = 40;
  constexpr int LIN_ELT = S * PITCH;
  constexpr int NSTG = (S * 4 + 255) / 256;
  static_assert(PW >= OW + K - 1, "");
  __shared__ __align__(16) ushort lin[2][LIN_ELT];
  const int n = blockIdx.x;
  const int r0 = blockIdx.y * TR;
  const int t = threadIdx.x;
  const int wv = t >> 6;
  const int lane = t & 63;
  const int nn = lane & 15;
  const int q = lane >> 4;
  f32x4 acc0[NCH], acc1[NCH];
  int boff[NCH];
#pragma unroll
  for (int c = 0; c < NCH; c++) {
    acc0[c] = f32x4{0.f, 0.f, 0.f, 0.f};
    acc1[c] = f32x4{0.f, 0.f, 0.f, 0.f};
    int p = c * 16 + nn;
    int pc = p < NPOS ? p : NPOS - 1;
    boff[c] = ((pc / OW) * PW + (pc % OW)) * PITCH + q * 8;
  }
  s16x8 stg[NSTG];
  auto load_stage = [&](int ci0) {
#pragma unroll
    for (int i = 0; i < NSTG; i++) {
      int e = t + i * 256;
      s16x8 v = {0, 0, 0, 0, 0, 0, 0, 0};
      if (e < S * 4) {
        int sp = e >> 2, j = e & 3;
        int rr = sp / PW, cc = sp - rr * PW;
        int ir = r0 + rr - PAD, ic = cc - PAD;
        if (ir >= 0 && ir < IH && ic >= 0 && ic < IW)
          v = *(const s16x8*)&in[((size_t)n * (IH * IW) + ir * IW + ic) * 128 +
                                 ci0 + j * 8];
      }
      stg[i] = v;
    }
  };
  auto store_stage = [&](int bsel) {
#pragma unroll
    for (int i = 0; i < NSTG; i++) {
      int e = t + i * 256;
      if (e < S * 4) {
        int sp = e >> 2, j = e & 3;
        *(s16x8*)&lin[bsel][sp * PITCH + j * 8] = stg[i];
      }
    }
  };

  load_stage(0);
  store_stage(0);
  __syncthreads();
  for (int cb = 0; cb < 4; cb++) {
    const int ci0 = cb * 32;
    if (cb < 3) load_stage(ci0 + 32);
    const ushort* L = lin[cb & 1];
    const size_t gA = (size_t)(wv * 16 + nn) * 128 + ci0 + q * 8;
    const size_t gB = (size_t)((wv + 4) * 16 + nn) * 128 + ci0 + q * 8;
    s16x8 ca0 = *(const s16x8*)&wprep[gA];
    s16x8 ca1 = *(const s16x8*)&wprep[gB];
    for (int tap = 0; tap < K2; tap++) {
      s16x8 na0 = ca0, na1 = ca1;
      if (tap + 1 < K2) {
        na0 = *(const s16x8*)&wprep[gA + (size_t)(tap + 1) * 16384];
        na1 = *(const s16x8*)&wprep[gB + (size_t)(tap + 1) * 16384];
      }
      const int ky = tap / K, kx = tap - ky * K;
      const int tp = (ky * PW + kx) * PITCH;
#pragma unroll
      for (int c = 0; c < NCH; c++) {
        s16x8 b = *(const s16x8*)&L[boff[c] + tp];
        acc0[c] =
            __builtin_amdgcn_mfma_f32_16x16x32_bf16(ca0, b, acc0[c], 0, 0, 0);
        acc1[c] =
            __builtin_amdgcn_mfma_f32_16x16x32_bf16(ca1, b, acc1[c], 0, 0, 0);
      }
      ca0 = na0; ca1 = na1;
    }
    if (cb < 3) {
      store_stage((cb + 1) & 1);
      __syncthreads();
    }
  }
  const int co_a = wv * 16 + q * 4;
  const int co_b = (wv + 4) * 16 + q * 4;
  float ba[4], bb[4];
#pragma unroll
  for (int r = 0; r < 4; r++) {
    ba[r] = bias[co_a + r];
    bb[r] = bias[co_b + r];
  }
  if (!MU_FUSE) {
    ushort* out = (ushort*)outp;
#pragma unroll
    for (int c = 0; c < NCH; c++) {
      int p = c * 16 + nn;
      if (p < NPOS) {
        size_t go = ((size_t)n * (OH * OW) + r0 * OW + p) * 128;
        s16x4 pa, pb;
#pragma unroll
        for (int r = 0; r < 4; r++) {
          pa[r] = (short)f2bf(fmaxf(acc0[c][r] + ba[r], 0.f));
          pb[r] = (short)f2bf(fmaxf(acc1[c][r] + bb[r], 0.f));
        }
        *(s16x4*)&out[go + co_a] = pa;
        *(s16x4*)&out[go + co_b] = pb;
      }
    }
  } else {
    float* out = (float*)outp;
    float wa[4], wb[4];
#pragma unroll
    for (int r = 0; r < 4; r++) {
      wa[r] = mw[co_a + r];
      wb[r] = mw[co_b + r];
    }
#pragma unroll
    for (int c = 0; c < NCH; c++) {
      int p = c * 16 + nn;
      float s = 0.f;
#pragma unroll
      for (int r = 0; r < 4; r++) {
        s += fmaxf(acc0[c][r] + ba[r], 0.f) * wa[r];
        s += fmaxf(acc1[c][r] + bb[r], 0.f) * wb[r];
      }
      s += __shfl_xor(s, 16);
      s += __shfl_xor(s, 32);
      if (q == 0 && p < NPOS)
        atomicAdd(&out[(size_t)n * (OH * OW) + r0 * OW + p], s);
    }
  }
}

// ---------------- t2: k4 s2 deconv via parity decomposition, bf16 NHWC ------
__global__ __launch_bounds__(256, 3) void deconv_s2_mfma(
    const ushort* __restrict__ in, const ushort* __restrict__ wp2,
    const float* __restrict__ bias, ushort* __restrict__ out) {
  constexpr int NCH = 7;
  constexpr int PITCH = 40;
  constexpr int PW = 18;
  constexpr int S = 11 * PW;
  const int n = blockIdx.x;
  const int pp = blockIdx.y;
  const int py = pp >> 1, px = pp & 1;
  __shared__ __align__(16) ushort lin[S * PITCH];
  const int t = threadIdx.x;
  const int wv = t >> 6;
  const int lane = t & 63;
  const int nn = lane & 15;
  const int q = lane >> 4;
  f32x4 acc0[NCH], acc1[NCH];
  int boff[NCH];
#pragma unroll
  for (int c = 0; c < NCH; c++) {
    acc0[c] = f32x4{0.f, 0.f, 0.f, 0.f};
    acc1[c] = f32x4{0.f, 0.f, 0.f, 0.f};
    int p = c * 16 + nn;
    int pc = p < 100 ? p : 99;
    boff[c] = ((pc / 10) * PW + (pc % 10)) * PITCH + q * 8;
  }
  const int toffs[4] = {PW + 1, PW, 1, 0};
  for (int cb = 0; cb < 4; cb++) {
    const int ci0 = cb * 32;
    __syncthreads();
    for (int e = t; e < S * 4; e += 256) {
      int sp = e >> 2, j = e & 3;
      int r = sp / PW, c2 = sp - r * PW;
      int ir = r - 1, ic = c2 - 1;
      s16x8 v = {0, 0, 0, 0, 0, 0, 0, 0};
      if (ir >= 0 && ir < 9 && ic >= 0 && ic < 9)
        v = *(const s16x8*)&in[((size_t)n * 81 + ir * 9 + ic) * 128 + ci0 +
                               j * 8];
      *(s16x8*)&lin[sp * PITCH + j * 8] = v;
    }
    __syncthreads();
    const size_t gA =
        ((size_t)(pp * 4) * 128 + wv * 16 + nn) * 128 + ci0 + q * 8;
    const size_t gB =
        ((size_t)(pp * 4) * 128 + (wv + 4) * 16 + nn) * 128 + ci0 + q * 8;
    s16x8 ca0 = *(const s16x8*)&wp2[gA];
    s16x8 ca1 = *(const s16x8*)&wp2[gB];
    for (int tap = 0; tap < 4; tap++) {
      s16x8 na0 = ca0, na1 = ca1;
      if (tap + 1 < 4) {
        na0 = *(const s16x8*)&wp2[gA + (size_t)(tap + 1) * 16384];
        na1 = *(const s16x8*)&wp2[gB + (size_t)(tap + 1) * 16384];
      }
      const int tp = toffs[tap] * PITCH;
#pragma unroll
      for (int c = 0; c < NCH; c++) {
        s16x8 b = *(const s16x8*)&lin[boff[c] + tp];
        acc0[c] =
            __builtin_amdgcn_mfma_f32_16x16x32_bf16(ca0, b, acc0[c], 0, 0, 0);
        acc1[c] =
            __builtin_amdgcn_mfma_f32_16x16x32_bf16(ca1, b, acc1[c], 0, 0, 0);
      }
      ca0 = na0; ca1 = na1;
    }
  }
  const int co_a = wv * 16 + q * 4;
  const int co_b = (wv + 4) * 16 + q * 4;
#pragma unroll
  for (int c = 0; c < NCH; c++) {
    int p = c * 16 + nn;
    if (p < 100) {
      int oy = 2 * (p / 10) + py, ox = 2 * (p % 10) + px;
      size_t go = ((size_t)n * 400 + oy * 20 + ox) * 128;
      s16x4 pa, pb;
#pragma unroll
      for (int r = 0; r < 4; r++) {
        pa[r] = (short)f2bf(fmaxf(acc0[c][r] + bias[co_a + r], 0.f));
        pb[r] = (short)f2bf(fmaxf(acc1[c][r] + bias[co_b + r], 0.f));
      }
      *(s16x4*)&out[go + co_a] = pa;
      *(s16x4*)&out[go + co_b] = pb;
    }
  }
}

// ---------------- rec loss ([0,196) blocks, float4); dict/enc in vq ---------
__global__ __launch_bounds__(256) void loss_kernel(
    const float4* __restrict__ mu4, const float* __restrict__ mb,
    const float4* __restrict__ x4, float* __restrict__ out) {
  const int b = blockIdx.x, t = threadIdx.x;
  __shared__ float red[256];
  int i = b * 256 + t;
  float4 m = mu4[i], xx = x4[i];
  float b0 = mb[0];
  float d0 = m.x + b0 - xx.x;
  float d1 = m.y + b0 - xx.y;
  float d2 = m.z + b0 - xx.z;
  float d3 = m.w + b0 - xx.w;
  red[t] = d0 * d0 + d1 * d1 + d2 * d2 + d3 * d3;
  __syncthreads();
  for (int off = 128; off > 0; off >>= 1) {
    if (t < off) red[t] += red[t + off];
    __syncthreads();
  }
  if (t == 0) atomicAdd(out, red[0] * (1.0f / 200704.f));
}

// ---------------------------------------------------------------------------
extern "C" void kernel_launch(void* const* d_in, const int* in_sizes, int n_in,
                              void* d_out, int out_size, void* d_ws,
                              size_t ws_size, hipStream_t stream) {
  const float* x = (const float*)d_in[0];
  const float* w1 = (const float*)d_in[1];
  const float* b1 = (const float*)d_in[2];
  const float* w2 = (const float*)d_in[3];
  const float* b2 = (const float*)d_in[4];
  const float* w3 = (const float*)d_in[5];
  const float* b3 = (const float*)d_in[6];
  const float* t1w = (const float*)d_in[7];
  const float* t1b = (const float*)d_in[8];
  const float* t2w = (const float*)d_in[9];
  const float* t2b = (const float*)d_in[10];
  const float* t3w = (const float*)d_in[11];
  const float* t3b = (const float*)d_in[12];
  const float* t4w = (const float*)d_in[13];
  const float* t4b = (const float*)d_in[14];
  const float* mw = (const float*)d_in[15];
  const float* mb = (const float*)d_in[16];
  const float* dictw = (const float*)d_in[17];
  float* out = (float*)d_out;

  float* p = (float*)d_ws;
  _Float16* h1h = (_Float16*)p; p += 9437184;
  _Float16* h1l = (_Float16*)p; p += 9437184;
  _Float16* p1h = (_Float16*)p; p += 2359296;
  _Float16* p1l = (_Float16*)p; p += 2359296;
  float* z = p; p += 1179648;
  float* val = p; p += 1179648;
  ushort* val_bf = (ushort*)p; p += 589824;
  float* mu = p; p += 200704;
  ushort* wp1 = (ushort*)p; p += 131072;
  ushort* wp3 = (ushort*)p; p += 204800;
  ushort* wp4 = (ushort*)p; p += 204800;
  ushort* wp2 = (ushort*)p; p += 131072;
  _Float16* w2h = (_Float16*)p; p += 204800;
  _Float16* w2l = (_Float16*)p; p += 204800;
  _Float16* w3h = (_Float16*)p; p += 204800;
  _Float16* w3l = (_Float16*)p; p += 204800;
  // aliases (dead buffers reused):
  ushort* f1 = (ushort*)p1h;  // (256,81,128) bf16
  ushort* f2 = (ushort*)h1l;  // (256,400,128) bf16
  ushort* f3 = (ushort*)h1h;  // (256,576,128) bf16

  hipMemsetAsync(d_out, 0, 4 * sizeof(float), stream);
  hipMemsetAsync(mu, 0, 200704 * sizeof(float), stream);

  prep_all<<<8448, 256, 0, stream>>>(t1w, t3w, t4w, t2w, w2, w3, wp1, wp3, wp4,
                                     wp2, w2h, w2l, w3h, w3l);

  conv1_kernel<<<B_, 256, 0, stream>>>(x, w1, b1, h1h, h1l);
  // conv2: 24x24 K5 pad2 relu + pool -> p1 hi/lo NHWC (12x12), TR=6, PW=28
  conv_mfma_pool<24, 5, 2, 6, true, false, 28>
      <<<dim3(B_, 4), 256, 0, stream>>>(h1h, h1l, w2h, w2l, b2, p1h, p1l,
                                        nullptr);
  // conv3: 12x12 K5 pad2 + pool -> z f32 NHWC (6x6), TR=4, PW=20 (OW+8)
  conv_mfma_pool<12, 5, 2, 4, false, true, 20>
      <<<dim3(B_, 3), 256, 0, stream>>>(p1h, p1l, w3h, w3l, b3, nullptr,
                                        nullptr, z);
  vq_kernel<<<B_, 256, 0, stream>>>(z, dictw, val, val_bf, out + 4, out);
  // t1: 6->9, K4 s1, relu  [bf16 NHWC, dbuf], PW=17 (OW+8)
  deconv_mfma<6, 6, 9, 9, 4, 9, false, 17>
      <<<dim3(B_, 1), 256, 0, stream>>>(val_bf, wp1, t1b, nullptr, f1);
  // t2: 9->20, K4 s2, relu  [bf16 NHWC, parity decomposition], PW=18
  deconv_s2_mfma<<<dim3(B_, 4), 256, 0, stream>>>(f1, wp2, t2b, f2);
  // t3: 20->24, K5 s1, relu  [bf16 NHWC, dbuf], PW=28
  deconv_mfma<20, 20, 24, 24, 5, 8, false, 28>
      <<<dim3(B_, 3), 256, 0, stream>>>(f2, wp3, t3b, nullptr, f3);
  // t4: 24->28, K5 s1, relu + fused 1x1 mu  [bf16 NHWC, dbuf], PW=36
  deconv_mfma<24, 24, 28, 28, 5, 7, true, 36>
      <<<dim3(B_, 4), 256, 0, stream>>>(f3, wp4, t4b, mw, mu);
  loss_kernel<<<196, 256, 0, stream>>>((const float4*)mu, mb,
                                       (const float4*)x, out);
}

// Round 10
// 871.043 us; speedup vs baseline: 1.4831x; 1.0118x over previous
//
#include <hip/hip_runtime.h>
#include <hip/hip_bf16.h>

// ---------------------------------------------------------------------------
// VQ-VAE forward. R20: deconv occupancy fix + prep/conv1 merge.
//  - t1/t3/t4: single LDS buffer + register prefetch of next ci-slice
//    (R9-proven pattern). Halves deconv LDS (t4 63.4->31.7KB, t3 53.8->26.9)
//    so ALL blocks are co-resident (t4: 4/CU work, now 5/CU capacity;
//    t3: 3/CU work, 5/CU capacity) — barrier/staging stalls overlap across
//    blocks instead of idling the CU at 2 resident blocks. Wave structure
//    unchanged (2 A-frags — the only shape this compiler schedules well;
//    dedup abandoned after R14/15/16/18).
//  - prep_all merged into conv1 launch (disjoint blockIdx ranges, independent
//    work): overlaps prep under conv1, kills one launch gap.
// KEPT: conv2/conv3 R13 template (conv2 at structural limit: MFMA floor
// 175us = 61% of 287us wall, MfmaUtil 59.5%); vq-fused dict/enc losses;
// float4 rec loss; R13 linear LDS slot + PW padding.
// ---------------------------------------------------------------------------

#define B_ 256

typedef __attribute__((ext_vector_type(8))) short s16x8;
typedef __attribute__((ext_vector_type(4))) short s16x4;
typedef __attribute__((ext_vector_type(8))) _Float16 f16x8;
typedef __attribute__((ext_vector_type(4))) float f32x4;

__device__ inline ushort f2bf(float f) {
  union { __hip_bfloat16 h; ushort u; } cv;
  cv.h = __float2bfloat16(f);
  return cv.u;
}

// ------- merged: conv1 (blocks 0..255) + weight prep (blocks 256..8703) -----
__global__ __launch_bounds__(256) void conv1_prep_kernel(
    const float* __restrict__ x, const float* __restrict__ w1,
    const float* __restrict__ b1, _Float16* __restrict__ oh,
    _Float16* __restrict__ ol,
    const float* __restrict__ t1w, const float* __restrict__ t3w,
    const float* __restrict__ t4w, const float* __restrict__ t2w,
    const float* __restrict__ w2, const float* __restrict__ w3,
    ushort* __restrict__ wp1, ushort* __restrict__ wp3,
    ushort* __restrict__ wp4, ushort* __restrict__ wp2,
    _Float16* __restrict__ w2h, _Float16* __restrict__ w2l,
    _Float16* __restrict__ w3h, _Float16* __restrict__ w3l) {
  const int t = threadIdx.x;
  if (blockIdx.x < 256) {
    // ---- conv1: (B,1,28,28) -> NHWC hi/lo (B,576,128), 5x5, pad0, ReLU ----
    const int n = blockIdx.x;
    __shared__ float xl[784];
    __shared__ float wl[128 * 25];
    __shared__ float bl[128];
    for (int e = t; e < 784; e += 256) xl[e] = x[n * 784 + e];
    for (int e = t; e < 3200; e += 256) wl[e] = w1[e];
    if (t < 128) bl[t] = b1[t];
    __syncthreads();
    const size_t nb = (size_t)n * 73728;
    for (int idx = t; idx < 73728; idx += 256) {
      int co = idx & 127, p = idx >> 7;
      int y = p / 24, xx = p % 24;
      float acc = bl[co];
      const float* wc = &wl[co * 25];
#pragma unroll
      for (int ky = 0; ky < 5; ky++)
#pragma unroll
        for (int kx = 0; kx < 5; kx++)
          acc += xl[(y + ky) * 28 + xx + kx] * wc[ky * 5 + kx];
      float v = fmaxf(acc, 0.f);
      _Float16 h = (_Float16)v;
      oh[nb + idx] = h;
      ol[nb + idx] = (_Float16)(v - (float)h);
    }
    return;
  }
  const int b = blockIdx.x - 256;
  if (b < 1024) {
    int idx = b * 256 + t;
    int ci = idx & 127, co = (idx >> 7) & 127, tap = idx >> 14;
    wp1[idx] = f2bf(t1w[((size_t)ci * 128 + co) * 16 + (15 - tap)]);
  } else if (b < 2624) {
    int idx = (b - 1024) * 256 + t;
    int ci = idx & 127, co = (idx >> 7) & 127, tap = idx >> 14;
    wp3[idx] = f2bf(t3w[((size_t)ci * 128 + co) * 25 + (24 - tap)]);
  } else if (b < 4224) {
    int idx = (b - 2624) * 256 + t;
    int ci = idx & 127, co = (idx >> 7) & 127, tap = idx >> 14;
    wp4[idx] = f2bf(t4w[((size_t)ci * 128 + co) * 25 + (24 - tap)]);
  } else if (b < 5248) {
    int idx = (b - 4224) * 256 + t;
    int ci = idx & 127, co = (idx >> 7) & 127;
    int tap = (idx >> 14) & 3, pp = idx >> 16;
    int u = tap >> 1, v = tap & 1, py = pp >> 1, px = pp & 1;
    wp2[idx] = f2bf(
        t2w[(((size_t)ci * 128 + co) * 4 + (py + 2 * u)) * 4 + (px + 2 * v)]);
  } else if (b < 6848) {
    int idx = (b - 5248) * 256 + t;
    int ci = idx & 127, co = (idx >> 7) & 127, tap = idx >> 14;
    float v = w2[((size_t)co * 128 + ci) * 25 + tap];
    _Float16 h = (_Float16)v;
    w2h[idx] = h;
    w2l[idx] = (_Float16)(v - (float)h);
  } else {
    int idx = (b - 6848) * 256 + t;
    int ci = idx & 127, co = (idx >> 7) & 127, tap = idx >> 14;
    float v = w3[((size_t)co * 128 + ci) * 25 + tap];
    _Float16 h = (_Float16)v;
    w3h[idx] = h;
    w3l[idx] = (_Float16)(v - (float)h);
  }
}

// ---------------- split-fp16 MFMA conv + bias(+relu) + 2x2 maxpool ----------
// R13 generic template (conv2 + conv3). Linear LDS slot; PWX padded row.
template <int IW, int K, int PAD, int TR, bool RELU, bool OUT_F32, int PWX>
__global__ __launch_bounds__(256, 3) void conv_mfma_pool(
    const _Float16* __restrict__ inh, const _Float16* __restrict__ inl,
    const _Float16* __restrict__ wph, const _Float16* __restrict__ wpl,
    const float* __restrict__ bias, _Float16* __restrict__ outh,
    _Float16* __restrict__ outl, float* __restrict__ outf) {
  constexpr int IH = IW, OW = IW, OH = IW;
  constexpr int PW = PWX;
  constexpr int SROWS = TR + K - 1;
  constexpr int S = SROWS * PW;
  constexpr int NPOS = TR * OW;
  constexpr int NCH = NPOS / 16;
  constexpr int SCRP = NPOS + 1;
  constexpr int K2 = K * K;
  constexpr int PITCH = 40;
  constexpr int LIN_ELT = S * PITCH;
  constexpr int LIN_BYTES = 2 * LIN_ELT * 2;
  constexpr int SCR_BYTES = 64 * SCRP * 4;
  constexpr int SMEM_BYTES = LIN_BYTES > SCR_BYTES ? LIN_BYTES : SCR_BYTES;
  static_assert(NPOS % 16 == 0, "");
  static_assert(TR % 2 == 0 && OW % 2 == 0, "");
  static_assert(PW >= OW + K - 1, "");
  __shared__ __align__(16) char smem[SMEM_BYTES];
  _Float16* linh = (_Float16*)smem;
  _Float16* linl = linh + LIN_ELT;
  const int n = blockIdx.x;
  const int r0 = blockIdx.y * TR;
  const int t = threadIdx.x;
  const int wv = t >> 6;
  const int lane = t & 63;
  const int nn = lane & 15;
  const int q = lane >> 4;
  f32x4 acc0[NCH], acc1[NCH];
  int boff[NCH];
#pragma unroll
  for (int c = 0; c < NCH; c++) {
    acc0[c] = f32x4{0.f, 0.f, 0.f, 0.f};
    acc1[c] = f32x4{0.f, 0.f, 0.f, 0.f};
    int p = c * 16 + nn;
    boff[c] = ((p / OW) * PW + (p % OW)) * PITCH + q * 8;
  }
  const int rowA = wv * 16 + nn;
  const int rowB = (wv + 4) * 16 + nn;
  for (int cb = 0; cb < 4; cb++) {
    const int ci0 = cb * 32;
    __syncthreads();
    for (int e = t; e < S * 4; e += 256) {
      int sp = e >> 2, j = e & 3;
      int r = sp / PW, c = sp - r * PW;
      int ir = r0 + r - PAD, ic = c - PAD;
      f16x8 vh = {0, 0, 0, 0, 0, 0, 0, 0};
      f16x8 vl = {0, 0, 0, 0, 0, 0, 0, 0};
      if (ir >= 0 && ir < IH && ic >= 0 && ic < IW) {
        size_t g = ((size_t)n * (IH * IW) + ir * IW + ic) * 128 + ci0 + j * 8;
        vh = *(const f16x8*)&inh[g];
        vl = *(const f16x8*)&inl[g];
      }
      int st = sp * PITCH + j * 8;
      *(f16x8*)&linh[st] = vh;
      *(f16x8*)&linl[st] = vl;
    }
    __syncthreads();
    const size_t gA = (size_t)rowA * 128 + ci0 + q * 8;
    const size_t gB = (size_t)rowB * 128 + ci0 + q * 8;
    f16x8 cah0 = *(const f16x8*)&wph[gA];
    f16x8 cal0 = *(const f16x8*)&wpl[gA];
    f16x8 cah1 = *(const f16x8*)&wph[gB];
    f16x8 cal1 = *(const f16x8*)&wpl[gB];
    for (int tap = 0; tap < K2; tap++) {
      f16x8 nah0 = cah0, nal0 = cal0, nah1 = cah1, nal1 = cal1;
      if (tap + 1 < K2) {
        size_t oA = gA + (size_t)(tap + 1) * 16384;
        size_t oB = gB + (size_t)(tap + 1) * 16384;
        nah0 = *(const f16x8*)&wph[oA];
        nal0 = *(const f16x8*)&wpl[oA];
        nah1 = *(const f16x8*)&wph[oB];
        nal1 = *(const f16x8*)&wpl[oB];
      }
      const int ky = tap / K, kx = tap - ky * K;
      const int tp = (ky * PW + kx) * PITCH;
#pragma unroll
      for (int c = 0; c < NCH; c++) {
        int off = boff[c] + tp;
        f16x8 bh = *(const f16x8*)&linh[off];
        f16x8 bl = *(const f16x8*)&linl[off];
        acc0[c] =
            __builtin_amdgcn_mfma_f32_16x16x32_f16(cah0, bh, acc0[c], 0, 0, 0);
        acc0[c] =
            __builtin_amdgcn_mfma_f32_16x16x32_f16(cah0, bl, acc0[c], 0, 0, 0);
        acc0[c] =
            __builtin_amdgcn_mfma_f32_16x16x32_f16(cal0, bh, acc0[c], 0, 0, 0);
        acc1[c] =
            __builtin_amdgcn_mfma_f32_16x16x32_f16(cah1, bh, acc1[c], 0, 0, 0);
        acc1[c] =
            __builtin_amdgcn_mfma_f32_16x16x32_f16(cah1, bl, acc1[c], 0, 0, 0);
        acc1[c] =
            __builtin_amdgcn_mfma_f32_16x16x32_f16(cal1, bh, acc1[c], 0, 0, 0);
      }
      cah0 = nah0; cal0 = nal0; cah1 = nah1; cal1 = nal1;
    }
  }
  __syncthreads();
  float* scr = (float*)smem + wv * 16 * SCRP;
#pragma unroll
  for (int j = 0; j < 2; j++) {
    const int cot = (j ? wv + 4 : wv) * 16;
#pragma unroll
    for (int c = 0; c < NCH; c++) {
      f32x4 a = j ? acc1[c] : acc0[c];
#pragma unroll
      for (int r = 0; r < 4; r++) {
        float v = a[r] + bias[cot + q * 4 + r];
        if (RELU) v = fmaxf(v, 0.f);
        scr[(q * 4 + r) * SCRP + c * 16 + nn] = v;
      }
    }
    __syncthreads();
    for (int e = lane; e < 16 * (TR / 2) * (OW / 2); e += 64) {
      int co_l = e & 15;
      int rem = e >> 4;
      int pr = rem / (OW / 2), pc = rem - pr * (OW / 2);
      const float* s = scr + co_l * SCRP;
      int lp = (2 * pr) * OW + 2 * pc;
      float m =
          fmaxf(fmaxf(s[lp], s[lp + 1]), fmaxf(s[lp + OW], s[lp + OW + 1]));
      int sp_out = (r0 / 2 + pr) * (OW / 2) + pc;
      size_t go =
          ((size_t)n * ((OH / 2) * (OW / 2)) + sp_out) * 128 + cot + co_l;
      if (OUT_F32) {
        outf[go] = m;
      } else {
        _Float16 h = (_Float16)m;
        outh[go] = h;
        outl[go] = (_Float16)(m - (float)h);
      }
    }
    __syncthreads();
  }
}

// ---------------- VQ on NHWC z: argmax(d2), gather + fused dict/enc loss ----
__global__ __launch_bounds__(256) void vq_kernel(
    const float* __restrict__ z, const float* __restrict__ dict,
    float* __restrict__ val, ushort* __restrict__ val_bf,
    float* __restrict__ out_idx, float* __restrict__ out) {
  const int n = blockIdx.x;
  __shared__ float zl[36 * 128];
  __shared__ float d2[36 * 129];
  __shared__ float w2n[128];
  __shared__ int bk[36];
  __shared__ float red[256];
  const int t = threadIdx.x;
  const float* zn = z + (size_t)n * 4608;
  for (int e = t; e < 4608; e += 256) zl[e] = zn[e];
  if (t < 128) {
    float s = 0.f;
    const float* wr = dict + t * 128;
    for (int c = 0; c < 128; c++) s += wr[c] * wr[c];
    w2n[t] = s;
  }
  __syncthreads();
  const int k = t & 127, pg = t >> 7;
  float dot[18];
#pragma unroll
  for (int i = 0; i < 18; i++) dot[i] = 0.f;
  const float* wr = dict + k * 128;
  for (int c = 0; c < 128; c++) {
    float wv = wr[c];
#pragma unroll
    for (int i = 0; i < 18; i++) dot[i] += zl[(pg * 18 + i) * 128 + c] * wv;
  }
  float wn = w2n[k];
#pragma unroll
  for (int i = 0; i < 18; i++) d2[(pg * 18 + i) * 129 + k] = wn - 2.f * dot[i];
  __syncthreads();
  if (t < 36) {
    const float* dr = &d2[t * 129];
    float best = dr[0];
    int bi = 0;
    for (int kk = 1; kk < 128; kk++) {
      float v = dr[kk];
      if (v > best) { best = v; bi = kk; }  // strict >: first max (argmax tie)
    }
    bk[t] = bi;
    out_idx[n * 36 + t] = (float)bi;
  }
  __syncthreads();
  float* vn = val + (size_t)n * 4608;
  ushort* vbn = val_bf + (size_t)n * 4608;
  float lsum = 0.f;
  for (int e = t; e < 4608; e += 256) {
    int c = e & 127, p = e >> 7;
    float v = dict[bk[p] * 128 + c];
    vn[e] = v;
    vbn[e] = f2bf(v);
    float d = v - zl[e];
    lsum += d * d;
  }
  red[t] = lsum;
  __syncthreads();
  for (int off = 128; off > 0; off >>= 1) {
    if (t < off) red[t] += red[t + off];
    __syncthreads();
  }
  if (t == 0) {
    atomicAdd(out + 1, red[0] * (5.f / 1179648.f));
    atomicAdd(out + 2, red[0] * (1.25f / 1179648.f));
  }
}

// ---- bf16 MFMA deconv (s1), NHWC bf16 io, SINGLE LDS buffer + reg-prefetch,
// opt. mu. R20: halved LDS doubles resident blocks (t4 2->5/CU capacity);
// next ci-slice prefetched into regs before tap loop, stored after 2-barrier
// handoff (R9-proven pattern). Wave structure: 2 A-frags (unchanged).
template <int IH, int IW, int OH, int OW, int K, int TR, bool MU_FUSE, int PWX>
__global__ __launch_bounds__(256, 2) void deconv_mfma(
    const ushort* __restrict__ in, const ushort* __restrict__ wprep,
    const float* __restrict__ bias, const float* __restrict__ mw,
    void* __restrict__ outp) {
  constexpr int PAD = K - 1;
  constexpr int PW = PWX;
  constexpr int K2 = K * K;
  constexpr int SROWS = TR + K - 1;
  constexpr int S = SROWS * PW;
  constexpr int NPOS = TR * OW;
  constexpr int NCH = (NPOS + 15) / 16;
  constexpr int PITCH = 40;
  constexpr int LIN_ELT = S * PITCH;
  constexpr int NSTG = (S * 4 + 255) / 256;
  static_assert(PW >= OW + K - 1, "");
  __shared__ __align__(16) ushort lin[LIN_ELT];
  const int n = blockIdx.x;
  const int r0 = blockIdx.y * TR;
  const int t = threadIdx.x;
  const int wv = t >> 6;
  const int lane = t & 63;
  const int nn = lane & 15;
  const int q = lane >> 4;
  f32x4 acc0[NCH], acc1[NCH];
  int boff[NCH];
#pragma unroll
  for (int c = 0; c < NCH; c++) {
    acc0[c] = f32x4{0.f, 0.f, 0.f, 0.f};
    acc1[c] = f32x4{0.f, 0.f, 0.f, 0.f};
    int p = c * 16 + nn;
    int pc = p < NPOS ? p : NPOS - 1;
    boff[c] = ((pc / OW) * PW + (pc % OW)) * PITCH + q * 8;
  }
  s16x8 stg[NSTG];
  auto load_stage = [&](int ci0) {
#pragma unroll
    for (int i = 0; i < NSTG; i++) {
      int e = t + i * 256;
      s16x8 v = {0, 0, 0, 0, 0, 0, 0, 0};
      if (e < S * 4) {
        int sp = e >> 2, j = e & 3;
        int rr = sp / PW, cc = sp - rr * PW;
        int ir = r0 + rr - PAD, ic = cc - PAD;
        if (ir >= 0 && ir < IH && ic >= 0 && ic < IW)
          v = *(const s16x8*)&in[((size_t)n * (IH * IW) + ir * IW + ic) * 128 +
                                 ci0 + j * 8];
      }
      stg[i] = v;
    }
  };
  auto store_stage = [&]() {
#pragma unroll
    for (int i = 0; i < NSTG; i++) {
      int e = t + i * 256;
      if (e < S * 4) {
        int sp = e >> 2, j = e & 3;
        *(s16x8*)&lin[sp * PITCH + j * 8] = stg[i];
      }
    }
  };

  load_stage(0);
  store_stage();
  __syncthreads();
  for (int cb = 0; cb < 4; cb++) {
    const int ci0 = cb * 32;
    if (cb < 3) load_stage(ci0 + 32);  // prefetch next slice into regs
    const size_t gA = (size_t)(wv * 16 + nn) * 128 + ci0 + q * 8;
    const size_t gB = (size_t)((wv + 4) * 16 + nn) * 128 + ci0 + q * 8;
    s16x8 ca0 = *(const s16x8*)&wprep[gA];
    s16x8 ca1 = *(const s16x8*)&wprep[gB];
    for (int tap = 0; tap < K2; tap++) {
      s16x8 na0 = ca0, na1 = ca1;
      if (tap + 1 < K2) {
        na0 = *(const s16x8*)&wprep[gA + (size_t)(tap + 1) * 16384];
        na1 = *(const s16x8*)&wprep[gB + (size_t)(tap + 1) * 16384];
      }
      const int ky = tap / K, kx = tap - ky * K;
      const int tp = (ky * PW + kx) * PITCH;
#pragma unroll
      for (int c = 0; c < NCH; c++) {
        s16x8 b = *(const s16x8*)&lin[boff[c] + tp];
        acc0[c] =
            __builtin_amdgcn_mfma_f32_16x16x32_bf16(ca0, b, acc0[c], 0, 0, 0);
        acc1[c] =
            __builtin_amdgcn_mfma_f32_16x16x32_bf16(ca1, b, acc1[c], 0, 0, 0);
      }
      ca0 = na0; ca1 = na1;
    }
    if (cb < 3) {
      __syncthreads();   // all waves done reading current slice
      store_stage();
      __syncthreads();   // stores visible
    }
  }
  const int co_a = wv * 16 + q * 4;
  const int co_b = (wv + 4) * 16 + q * 4;
  float ba[4], bb[4];
#pragma unroll
  for (int r = 0; r < 4; r++) {
    ba[r] = bias[co_a + r];
    bb[r] = bias[co_b + r];
  }
  if (!MU_FUSE) {
    ushort* out = (ushort*)outp;
#pragma unroll
    for (int c = 0; c < NCH; c++) {
      int p = c * 16 + nn;
      if (p < NPOS) {
        size_t go = ((size_t)n * (OH * OW) + r0 * OW + p) * 128;
        s16x4 pa, pb;
#pragma unroll
        for (int r = 0; r < 4; r++) {
          pa[r] = (short)f2bf(fmaxf(acc0[c][r] + ba[r], 0.f));
          pb[r] = (short)f2bf(fmaxf(acc1[c][r] + bb[r], 0.f));
        }
        *(s16x4*)&out[go + co_a] = pa;
        *(s16x4*)&out[go + co_b] = pb;
      }
    }
  } else {
    float* out = (float*)outp;
    float wa[4], wb[4];
#pragma unroll
    for (int r = 0; r < 4; r++) {
      wa[r] = mw[co_a + r];
      wb[r] = mw[co_b + r];
    }
#pragma unroll
    for (int c = 0; c < NCH; c++) {
      int p = c * 16 + nn;
      float s = 0.f;
#pragma unroll
      for (int r = 0; r < 4; r++) {
        s += fmaxf(acc0[c][r] + ba[r], 0.f) * wa[r];
        s += fmaxf(acc1[c][r] + bb[r], 0.f) * wb[r];
      }
      s += __shfl_xor(s, 16);
      s += __shfl_xor(s, 32);
      if (q == 0 && p < NPOS)
        atomicAdd(&out[(size_t)n * (OH * OW) + r0 * OW + p], s);
    }
  }
}

// ---------------- t2: k4 s2 deconv via parity decomposition, bf16 NHWC ------
__global__ __launch_bounds__(256, 3) void deconv_s2_mfma(
    const ushort* __restrict__ in, const ushort* __restrict__ wp2,
    const float* __restrict__ bias, ushort* __restrict__ out) {
  constexpr int NCH = 7;
  constexpr int PITCH = 40;
  constexpr int PW = 18;
  constexpr int S = 11 * PW;
  const int n = blockIdx.x;
  const int pp = blockIdx.y;
  const int py = pp >> 1, px = pp & 1;
  __shared__ __align__(16) ushort lin[S * PITCH];
  const int t = threadIdx.x;
  const int wv = t >> 6;
  const int lane = t & 63;
  const int nn = lane & 15;
  const int q = lane >> 4;
  f32x4 acc0[NCH], acc1[NCH];
  int boff[NCH];
#pragma unroll
  for (int c = 0; c < NCH; c++) {
    acc0[c] = f32x4{0.f, 0.f, 0.f, 0.f};
    acc1[c] = f32x4{0.f, 0.f, 0.f, 0.f};
    int p = c * 16 + nn;
    int pc = p < 100 ? p : 99;
    boff[c] = ((pc / 10) * PW + (pc % 10)) * PITCH + q * 8;
  }
  const int toffs[4] = {PW + 1, PW, 1, 0};
  for (int cb = 0; cb < 4; cb++) {
    const int ci0 = cb * 32;
    __syncthreads();
    for (int e = t; e < S * 4; e += 256) {
      int sp = e >> 2, j = e & 3;
      int r = sp / PW, c2 = sp - r * PW;
      int ir = r - 1, ic = c2 - 1;
      s16x8 v = {0, 0, 0, 0, 0, 0, 0, 0};
      if (ir >= 0 && ir < 9 && ic >= 0 && ic < 9)
        v = *(const s16x8*)&in[((size_t)n * 81 + ir * 9 + ic) * 128 + ci0 +
                               j * 8];
      *(s16x8*)&lin[sp * PITCH + j * 8] = v;
    }
    __syncthreads();
    const size_t gA =
        ((size_t)(pp * 4) * 128 + wv * 16 + nn) * 128 + ci0 + q * 8;
    const size_t gB =
        ((size_t)(pp * 4) * 128 + (wv + 4) * 16 + nn) * 128 + ci0 + q * 8;
    s16x8 ca0 = *(const s16x8*)&wp2[gA];
    s16x8 ca1 = *(const s16x8*)&wp2[gB];
    for (int tap = 0; tap < 4; tap++) {
      s16x8 na0 = ca0, na1 = ca1;
      if (tap + 1 < 4) {
        na0 = *(const s16x8*)&wp2[gA + (size_t)(tap + 1) * 16384];
        na1 = *(const s16x8*)&wp2[gB + (size_t)(tap + 1) * 16384];
      }
      const int tp = toffs[tap] * PITCH;
#pragma unroll
      for (int c = 0; c < NCH; c++) {
        s16x8 b = *(const s16x8*)&lin[boff[c] + tp];
        acc0[c] =
            __builtin_amdgcn_mfma_f32_16x16x32_bf16(ca0, b, acc0[c], 0, 0, 0);
        acc1[c] =
            __builtin_amdgcn_mfma_f32_16x16x32_bf16(ca1, b, acc1[c], 0, 0, 0);
      }
      ca0 = na0; ca1 = na1;
    }
  }
  const int co_a = wv * 16 + q * 4;
  const int co_b = (wv + 4) * 16 + q * 4;
#pragma unroll
  for (int c = 0; c < NCH; c++) {
    int p = c * 16 + nn;
    if (p < 100) {
      int oy = 2 * (p / 10) + py, ox = 2 * (p % 10) + px;
      size_t go = ((size_t)n * 400 + oy * 20 + ox) * 128;
      s16x4 pa, pb;
#pragma unroll
      for (int r = 0; r < 4; r++) {
        pa[r] = (short)f2bf(fmaxf(acc0[c][r] + bias[co_a + r], 0.f));
        pb[r] = (short)f2bf(fmaxf(acc1[c][r] + bias[co_b + r], 0.f));
      }
      *(s16x4*)&out[go + co_a] = pa;
      *(s16x4*)&out[go + co_b] = pb;
    }
  }
}

// ---------------- rec loss ([0,196) blocks, float4); dict/enc in vq ---------
__global__ __launch_bounds__(256) void loss_kernel(
    const float4* __restrict__ mu4, const float* __restrict__ mb,
    const float4* __restrict__ x4, float* __restrict__ out) {
  const int b = blockIdx.x, t = threadIdx.x;
  __shared__ float red[256];
  int i = b * 256 + t;
  float4 m = mu4[i], xx = x4[i];
  float b0 = mb[0];
  float d0 = m.x + b0 - xx.x;
  float d1 = m.y + b0 - xx.y;
  float d2 = m.z + b0 - xx.z;
  float d3 = m.w + b0 - xx.w;
  red[t] = d0 * d0 + d1 * d1 + d2 * d2 + d3 * d3;
  __syncthreads();
  for (int off = 128; off > 0; off >>= 1) {
    if (t < off) red[t] += red[t + off];
    __syncthreads();
  }
  if (t == 0) atomicAdd(out, red[0] * (1.0f / 200704.f));
}

// ---------------------------------------------------------------------------
extern "C" void kernel_launch(void* const* d_in, const int* in_sizes, int n_in,
                              void* d_out, int out_size, void* d_ws,
                              size_t ws_size, hipStream_t stream) {
  const float* x = (const float*)d_in[0];
  const float* w1 = (const float*)d_in[1];
  const float* b1 = (const float*)d_in[2];
  const float* w2 = (const float*)d_in[3];
  const float* b2 = (const float*)d_in[4];
  const float* w3 = (const float*)d_in[5];
  const float* b3 = (const float*)d_in[6];
  const float* t1w = (const float*)d_in[7];
  const float* t1b = (const float*)d_in[8];
  const float* t2w = (const float*)d_in[9];
  const float* t2b = (const float*)d_in[10];
  const float* t3w = (const float*)d_in[11];
  const float* t3b = (const float*)d_in[12];
  const float* t4w = (const float*)d_in[13];
  const float* t4b = (const float*)d_in[14];
  const float* mw = (const float*)d_in[15];
  const float* mb = (const float*)d_in[16];
  const float* dictw = (const float*)d_in[17];
  float* out = (float*)d_out;

  float* p = (float*)d_ws;
  _Float16* h1h = (_Float16*)p; p += 9437184;
  _Float16* h1l = (_Float16*)p; p += 9437184;
  _Float16* p1h = (_Float16*)p; p += 2359296;
  _Float16* p1l = (_Float16*)p; p += 2359296;
  float* z = p; p += 1179648;
  float* val = p; p += 1179648;
  ushort* val_bf = (ushort*)p; p += 589824;
  float* mu = p; p += 200704;
  ushort* wp1 = (ushort*)p; p += 131072;
  ushort* wp3 = (ushort*)p; p += 204800;
  ushort* wp4 = (ushort*)p; p += 204800;
  ushort* wp2 = (ushort*)p; p += 131072;
  _Float16* w2h = (_Float16*)p; p += 204800;
  _Float16* w2l = (_Float16*)p; p += 204800;
  _Float16* w3h = (_Float16*)p; p += 204800;
  _Float16* w3l = (_Float16*)p; p += 204800;
  // aliases (dead buffers reused):
  ushort* f1 = (ushort*)p1h;  // (256,81,128) bf16
  ushort* f2 = (ushort*)h1l;  // (256,400,128) bf16
  ushort* f3 = (ushort*)h1h;  // (256,576,128) bf16

  hipMemsetAsync(d_out, 0, 4 * sizeof(float), stream);
  hipMemsetAsync(mu, 0, 200704 * sizeof(float), stream);

  // conv1 (blocks 0..255) + all weight prep (blocks 256..8703), one launch
  conv1_prep_kernel<<<8704, 256, 0, stream>>>(
      x, w1, b1, h1h, h1l, t1w, t3w, t4w, t2w, w2, w3, wp1, wp3, wp4, wp2,
      w2h, w2l, w3h, w3l);
  // conv2: 24x24 K5 pad2 relu + pool -> p1 hi/lo NHWC (12x12), TR=6, PW=28
  conv_mfma_pool<24, 5, 2, 6, true, false, 28>
      <<<dim3(B_, 4), 256, 0, stream>>>(h1h, h1l, w2h, w2l, b2, p1h, p1l,
                                        nullptr);
  // conv3: 12x12 K5 pad2 + pool -> z f32 NHWC (6x6), TR=4, PW=20 (OW+8)
  conv_mfma_pool<12, 5, 2, 4, false, true, 20>
      <<<dim3(B_, 3), 256, 0, stream>>>(p1h, p1l, w3h, w3l, b3, nullptr,
                                        nullptr, z);
  vq_kernel<<<B_, 256, 0, stream>>>(z, dictw, val, val_bf, out + 4, out);
  // t1: 6->9, K4 s1, relu  [bf16 NHWC, single-buf], PW=17 (OW+8)
  deconv_mfma<6, 6, 9, 9, 4, 9, false, 17>
      <<<dim3(B_, 1), 256, 0, stream>>>(val_bf, wp1, t1b, nullptr, f1);
  // t2: 9->20, K4 s2, relu  [bf16 NHWC, parity decomposition], PW=18
  deconv_s2_mfma<<<dim3(B_, 4), 256, 0, stream>>>(f1, wp2, t2b, f2);
  // t3: 20->24, K5 s1, relu  [bf16 NHWC, single-buf, 26.9KB -> 5 blk/CU]
  deconv_mfma<20, 20, 24, 24, 5, 8, false, 28>
      <<<dim3(B_, 3), 256, 0, stream>>>(f2, wp3, t3b, nullptr, f3);
  // t4: 24->28, K5 s1, relu + fused mu  [bf16 NHWC, single-buf, 31.7KB -> 5]
  deconv_mfma<24, 24, 28, 28, 5, 7, true, 36>
      <<<dim3(B_, 4), 256, 0, stream>>>(f3, wp4, t4b, mw, mu);
  loss_kernel<<<196, 256, 0, stream>>>((const float4*)mu, mb,
                                       (const float4*)x, out);
}